// Round 5
// baseline (40.516 us; speedup 1.0000x reference)
//
#include <hip/hip_runtime.h>
#include <hip/hip_fp16.h>

// JPEG layer: rgb->ycbcr (clamped) -> 8x8 2-D DCT.
// B=32, C=3, H=W=512 -> out [32,3,64,64,8,8] f32.
//
// v5: v4 + NON-TEMPORAL output stores. v4 counters showed input only ~half
// L3-resident (FETCH 49 MB of a 100 MB input): the 100 MB output write
// stream was evicting input lines from L3. Output has zero in-kernel reuse,
// so no-allocate ('nt') stores keep L3 for the input -> FETCH should drop
// toward 0 and HBM traffic approaches write-only (~105 MB).
//
// Structure (from v4): Phase A cooperative fp16 ycbcr staging (24 KB LDS,
// fused color transform, bulk float4 loads for MLP); Phase B per-lane 8x8
// stage-1 DCT from LDS; Phase C stage-2 DCT + per-wave LDS transpose so every
// global store instruction covers 16 FULL 64 B cache lines (v3->v4: 47->37 us).

#define HW (512 * 512)

typedef float f32x4 __attribute__((ext_vector_type(4)));

__device__ constexpr float DM[8][8] = {
    { 0.353553391f,  0.353553391f,  0.353553391f,  0.353553391f,
      0.353553391f,  0.353553391f,  0.353553391f,  0.353553391f },
    { 0.490392640f,  0.415734806f,  0.277785115f,  0.097545161f,
     -0.097545161f, -0.277785115f, -0.415734806f, -0.490392640f },
    { 0.461939766f,  0.191341716f, -0.191341716f, -0.461939766f,
     -0.461939766f, -0.191341716f,  0.191341716f,  0.461939766f },
    { 0.415734806f, -0.097545161f, -0.490392640f, -0.277785115f,
      0.277785115f,  0.490392640f,  0.097545161f, -0.415734806f },
    { 0.353553391f, -0.353553391f, -0.353553391f,  0.353553391f,
      0.353553391f, -0.353553391f, -0.353553391f,  0.353553391f },
    { 0.277785115f, -0.490392640f,  0.097545161f,  0.415734806f,
     -0.415734806f, -0.097545161f,  0.490392640f, -0.277785115f },
    { 0.191341716f, -0.461939766f,  0.461939766f, -0.191341716f,
     -0.191341716f,  0.461939766f, -0.461939766f,  0.191341716f },
    { 0.097545161f, -0.277785115f,  0.415734806f, -0.490392640f,
      0.490392640f, -0.415734806f,  0.277785115f, -0.097545161f }
};

__device__ __forceinline__ float clamp01(float v) {
    return fminf(fmaxf(v, 0.0f), 1.0f);
}

#define COFF (128.0f / 255.0f)

__device__ __forceinline__ void convert_quad(float4 r, float4 g, float4 bl,
                                             float4& y, float4& cb, float4& cr) {
    const float rv[4] = {r.x, r.y, r.z, r.w};
    const float gv[4] = {g.x, g.y, g.z, g.w};
    const float bv[4] = {bl.x, bl.y, bl.z, bl.w};
    float yo[4], cbo[4], cro[4];
    #pragma unroll
    for (int k = 0; k < 4; k++) {
        yo[k]  = clamp01(fmaf(0.299f, rv[k], fmaf(0.587f, gv[k], 0.114f * bv[k]))) - COFF;
        cbo[k] = clamp01(fmaf(-0.168735892f, rv[k],
                        fmaf(-0.331264108f, gv[k], fmaf(0.5f, bv[k], COFF)))) - COFF;
        cro[k] = clamp01(fmaf(0.5f, rv[k],
                        fmaf(-0.418687589f, gv[k], fmaf(-0.081312411f, bv[k], COFF)))) - COFF;
    }
    y  = make_float4(yo[0], yo[1], yo[2], yo[3]);
    cb = make_float4(cbo[0], cbo[1], cbo[2], cbo[3]);
    cr = make_float4(cro[0], cro[1], cro[2], cro[3]);
}

__device__ __forceinline__ void store_half4(__half* p, float4 v) {
    __half2* hp = (__half2*)p;
    hp[0] = __float22half2_rn(make_float2(v.x, v.y));
    hp[1] = __float22half2_rn(make_float2(v.z, v.w));
}

// 2048 WGs = (b, block_row). 192 threads = 3 waves.
__global__ __launch_bounds__(192, 4) void jpeg_dct(const float* __restrict__ rgb,
                                                   float* __restrict__ out) {
    __shared__ __align__(16) char smraw[24576];
    __half (*in)[8][512] = (__half (*)[8][512])smraw;   // [3][8][512] fp16, 24576 B
    float  (*tr)[64][20] = (float  (*)[64][20])smraw;   // [3][64][20]  f32, 15360 B

    const int wg = blockIdx.x;
    const int b  = wg >> 6;          // batch
    const int bh = wg & 63;          // block row
    const int t  = threadIdx.x;

    const float* rbase = rgb + (size_t)b * 3 * HW + (size_t)(bh * 8) * 512;

    // ---- Phase A: stage 1024 pixel-quads; thread t owns quads t, t+192, ... ----
    float4 R[6], G[6], Bv[6];
    #pragma unroll
    for (int it = 0; it < 5; it++) {
        const int q = t + it * 192;
        const int row = q >> 7, col4 = (q & 127) << 2;
        const float* p = rbase + row * 512 + col4;
        R[it]  = *(const float4*)(p);
        G[it]  = *(const float4*)(p + HW);
        Bv[it] = *(const float4*)(p + 2 * HW);
    }
    const bool extra = (t < 64);
    if (extra) {
        const int q = t + 960;
        const int row = q >> 7, col4 = (q & 127) << 2;
        const float* p = rbase + row * 512 + col4;
        R[5]  = *(const float4*)(p);
        G[5]  = *(const float4*)(p + HW);
        Bv[5] = *(const float4*)(p + 2 * HW);
    }
    #pragma unroll
    for (int it = 0; it < 5; it++) {
        const int q = t + it * 192;
        const int row = q >> 7, col4 = (q & 127) << 2;
        float4 y, cb, cr;
        convert_quad(R[it], G[it], Bv[it], y, cb, cr);
        store_half4(&in[0][row][col4], y);
        store_half4(&in[1][row][col4], cb);
        store_half4(&in[2][row][col4], cr);
    }
    if (extra) {
        const int q = t + 960;
        const int row = q >> 7, col4 = (q & 127) << 2;
        float4 y, cb, cr;
        convert_quad(R[5], G[5], Bv[5], y, cb, cr);
        store_half4(&in[0][row][col4], y);
        store_half4(&in[1][row][col4], cb);
        store_half4(&in[2][row][col4], cr);
    }
    __syncthreads();

    // ---- Phase B: wave c, lane bw -> stage-1 DCT (T = D @ X) from LDS ----
    const int c    = t >> 6;
    const int lane = t & 63;   // block column bw

    float T[8][8];
    #pragma unroll
    for (int i = 0; i < 8; i++)
        #pragma unroll
        for (int k = 0; k < 8; k++) T[i][k] = 0.0f;

    #pragma unroll
    for (int j = 0; j < 8; j++) {
        float4 raw = *(const float4*)&in[c][j][lane * 8];
        const __half2* hp = (const __half2*)&raw;
        float2 f0 = __half22float2(hp[0]);
        float2 f1 = __half22float2(hp[1]);
        float2 f2 = __half22float2(hp[2]);
        float2 f3 = __half22float2(hp[3]);
        const float x[8] = {f0.x, f0.y, f1.x, f1.y, f2.x, f2.y, f3.x, f3.y};
        #pragma unroll
        for (int i = 0; i < 8; i++) {
            const float d = DM[i][j];
            #pragma unroll
            for (int k = 0; k < 8; k++) T[i][k] = fmaf(d, x[k], T[i][k]);
        }
    }

    // all input-LDS reads done; LDS is re-purposed as transpose buffers
    __syncthreads();

    // ---- Phase C: stage-2 DCT, 2 output rows per round, transpose via LDS ----
    float* base2 = out + (size_t)((b * 3 + c) * 64 + bh) * 4096;

    #pragma unroll
    for (int r = 0; r < 4; r++) {
        #pragma unroll
        for (int ii = 0; ii < 2; ii++) {
            const int i = r * 2 + ii;
            float o[8];
            #pragma unroll
            for (int l = 0; l < 8; l++) {
                float s = T[i][0] * DM[l][0];
                #pragma unroll
                for (int k = 1; k < 8; k++) s = fmaf(T[i][k], DM[l][k], s);
                o[l] = s;
            }
            *(float4*)&tr[c][lane][ii * 8]     = make_float4(o[0], o[1], o[2], o[3]);
            *(float4*)&tr[c][lane][ii * 8 + 4] = make_float4(o[4], o[5], o[6], o[7]);
        }
        // wave-local write->read turn
        asm volatile("s_waitcnt lgkmcnt(0)" ::: "memory");
        // read transposed, store full 64B lines with no-allocate (nt) hint:
        // output has zero in-kernel reuse; keep L3 for the input stream.
        #pragma unroll
        for (int s = 0; s < 4; s++) {
            const int bws = s * 16 + (lane >> 2);      // source block-column
            const int mq  = (lane & 3) * 4;            // m'' quad within round
            const f32x4 v = *(const f32x4*)&tr[c][bws][mq];
            __builtin_nontemporal_store(v, (f32x4*)(base2 + bws * 64 + r * 16 + mq));
        }
        // WAR guard: reads of this round complete before next round's writes
        asm volatile("s_waitcnt lgkmcnt(0)" ::: "memory");
    }
}

extern "C" void kernel_launch(void* const* d_in, const int* in_sizes, int n_in,
                              void* d_out, int out_size, void* d_ws, size_t ws_size,
                              hipStream_t stream) {
    const float* rgb = (const float*)d_in[0];
    float* out = (float*)d_out;
    jpeg_dct<<<dim3(2048), dim3(192), 0, stream>>>(rgb, out);
}